// Round 4
// baseline (1645.586 us; speedup 1.0000x reference)
//
#include <hip/hip_runtime.h>
#include <math.h>

// Problem constants
#define BB 128
#define SS 512
#define HH 768
#define PPOS 512       // P
#define NEGC (-1.0e9f)
#define NINF (-1.0e12f)

// Workspace layout (float offsets). ALL DISJOINT (ws is 768 MiB; aliasing
// would risk stale-L1 reads across grid-barrier phases inside k_tail).
#define OFF_KVEC   0          // 2624  (41*64)
#define OFF_WEFF   2624       // 768
#define OFF_C      3392       // 1
#define OFF_SCORES 4096       // 65536 (B*S) raw masked scores
#define OFF_PP     69632      // 786432 (B*8*H) partial pooled
#define OFF_PS     856064     // 786432 partial subj max
#define OFF_PO     1642496    // 786432 partial obj max
#define OFF_POOLED 2428928    // 98304 (B*H)
#define OFF_CAT    2527232    // 294912 (B*2304) [subj|obj|ctx]
#define OFF_CTXA   2822144    // 98304
#define OFF_CTXB   2920448    // 98304
#define OFF_F1     3018752    // 98304
#define OFF_F2     3117056    // 38400 (B*300)
#define OFF_BAR    3155456    // 16 uints (grid barrier counters; atomics only)

#define NBLK 1024
#define NTHR 192

__device__ __forceinline__ float gelu_f(float x) {
    return 0.5f * x * (1.0f + erff(x * 0.70710678118654752f));
}
__device__ __forceinline__ float dot4(float4 a, float4 b) {
    return a.x*b.x + a.y*b.y + a.z*b.z + a.w*b.w;
}

// Grid barrier: all NBLK blocks co-resident (4 blocks/CU, enforced via
// __launch_bounds__(192,3) -> VGPR<=170), so spinning is safe.
__device__ __forceinline__ void gbar(unsigned* bar, unsigned nblk) {
    __syncthreads();
    if (threadIdx.x == 0) {
        __hip_atomic_fetch_add(bar, 1u, __ATOMIC_ACQ_REL, __HIP_MEMORY_SCOPE_AGENT);
        while (__hip_atomic_load(bar, __ATOMIC_ACQUIRE, __HIP_MEMORY_SCOPE_AGENT) < nblk)
            __builtin_amdgcn_s_sleep(2);
    }
    __syncthreads();
}

// Wave-tile GEMM phase: C[M,N] = act(A[M,K] @ W[N,K]^T + bias)
// wave computes MT(m) x 16(n); lane = (n_sub<<2)|k_sub; 2-step shuffle reduce.
template<int K4, int ACT, int MT>
__device__ __forceinline__ void mm_phase(const float* __restrict__ A,
        const float* __restrict__ W, const float* __restrict__ bias,
        float* __restrict__ C, int M, int N, int wv, int lane) {
    int ntn = (N + 15) >> 4;
    int m0 = (wv / ntn) * MT;
    if (m0 >= M) return;
    int n0 = ((wv % ntn) << 4) + (lane >> 2);
    int ks = lane & 3;
    bool nvalid = (n0 < N);
    const float4* w_row = (const float4*)W + (size_t)(nvalid ? n0 : 0) * K4;
    const float4* ar = (const float4*)A + (size_t)m0 * K4;
    float acc[MT];
    #pragma unroll
    for (int r = 0; r < MT; ++r) acc[r] = 0.f;
    #pragma unroll 4
    for (int j = ks; j < K4; j += 4) {
        float4 wvv = w_row[j];
        #pragma unroll
        for (int r = 0; r < MT; ++r) acc[r] += dot4(ar[(size_t)r * K4 + j], wvv);
    }
    #pragma unroll
    for (int r = 0; r < MT; ++r) {
        acc[r] += __shfl_xor(acc[r], 1, 64);
        acc[r] += __shfl_xor(acc[r], 2, 64);
    }
    if (ks == 0 && nvalid) {
        float b = bias ? bias[n0] : 0.f;
        #pragma unroll
        for (int r = 0; r < MT; ++r) {
            float v = acc[r] + b;
            if (ACT == 1) v = gelu_f(v);
            C[(size_t)(m0 + r) * N + n0] = v;
        }
    }
}

// K1a: kvec[l,k] = dot(label_emb[l+1], WK[l,k]) + bK. One wave/output.
// Blocks 0..3 zero-init WEFF and C for k_weff2's atomics.
__global__ __launch_bounds__(256) void k_kvec2(const float* __restrict__ label_emb,
        const float* __restrict__ WK, const float* __restrict__ bK,
        float* __restrict__ ws) {
    if (blockIdx.x < 3) ws[OFF_WEFF + blockIdx.x * 256 + threadIdx.x] = 0.f;
    if (blockIdx.x == 3 && threadIdx.x == 0) ws[OFF_C] = 0.f;
    int lane = threadIdx.x & 63;
    int idx = (blockIdx.x * 256 + threadIdx.x) >> 6;   // 0..2623
    int l = idx >> 6;
    const float4* lab4 = (const float4*)(label_emb + (size_t)(l + 1) * 300);
    const float4* wk4  = (const float4*)(WK + (size_t)idx * 300);
    float acc = dot4(lab4[lane], wk4[lane]);           // 75 float4s per row
    if (lane < 11) acc += dot4(lab4[64 + lane], wk4[64 + lane]);
    #pragma unroll
    for (int off = 32; off > 0; off >>= 1) acc += __shfl_xor(acc, off, 64);
    if (lane == 0) ws[OFF_KVEC + idx] = acc + bK[idx];
}

// K1b: w_eff[h] += kvec-chunk . WQ (atomics), + c = kvec.bQ
__global__ __launch_bounds__(256) void k_weff2(const float* __restrict__ WQ,
        const float* __restrict__ bQ, float* __restrict__ ws) {
    int lane = threadIdx.x & 63;
    int w = (blockIdx.x * 256 + threadIdx.x) >> 6;
    if (w < 492) {
        int jc = w / 12, hg = w % 12;
        int h = hg * 64 + lane;
        const float* wq = WQ + (size_t)(jc * 64) * HH + h;
        const float* kv = ws + OFF_KVEC + jc * 64;
        float acc = 0.f;
        #pragma unroll 8
        for (int j = 0; j < 64; ++j) acc += kv[j] * wq[(size_t)j * HH];
        atomicAdd(&ws[OFF_WEFF + h], acc);
    } else if (w == 492) {
        float acc = 0.f;
        for (int j = lane; j < 2624; j += 64) acc += ws[OFF_KVEC + j] * bQ[j];
        #pragma unroll
        for (int off = 32; off > 0; off >>= 1) acc += __shfl_xor(acc, off, 64);
        if (lane == 0) atomicAdd(&ws[OFF_C], acc);
    }
}

// K2: raw scores[row] = (x.w_eff + c)/8 + 41*mask*NEG. One wave/row, 8 rows/wave.
// Block 0 also zeroes the grid-barrier counters for k_tail.
__global__ __launch_bounds__(256) void k_scores(const float* __restrict__ inputs,
        const int* __restrict__ pos_ids, const int* __restrict__ subj_pos,
        const int* __restrict__ obj_pos, float* __restrict__ ws) {
    if (blockIdx.x == 0 && threadIdx.x < 16)
        ((unsigned*)(ws + OFF_BAR))[threadIdx.x] = 0u;
    int wave = threadIdx.x >> 6, lane = threadIdx.x & 63;
    const float4* in4 = (const float4*)inputs;
    const float4* w4  = (const float4*)(ws + OFF_WEFF);
    float c = ws[OFF_C];
    float4 w0 = w4[lane], w1 = w4[64 + lane], w2 = w4[128 + lane];
    int wid = blockIdx.x * 4 + wave;          // 0..8191
    for (int i = 0; i < 8; ++i) {
        int row = wid + 8192 * i;
        const float4* r4 = in4 + (size_t)row * 192;
        float acc = dot4(r4[lane], w0) + dot4(r4[64 + lane], w1) + dot4(r4[128 + lane], w2);
        #pragma unroll
        for (int off = 32; off > 0; off >>= 1) acc += __shfl_down(acc, off, 64);
        if (lane == 0) {
            bool m = (subj_pos[row] == PPOS) | (obj_pos[row] == PPOS) | (pos_ids[row] == 0);
            float sc = (acc + c) * 0.125f;
            if (m) sc += 41.0f * NEGC;
            ws[OFF_SCORES + row] = sc;
        }
    }
}

// K3: persistent fused tail. 1024 blocks x 192 threads, 7 grid barriers.
// P0 pool -> P1 reduce -> P2 ctxa -> P3 ctxb -> P4 ln -> P5 feat1 -> P6 feat2
// -> P7 logits.
__global__ __launch_bounds__(NTHR, 3) void k_tail(
        const float* __restrict__ inputs, const int* __restrict__ subj_pos,
        const int* __restrict__ obj_pos,
        const float* __restrict__ WV_w, const float* __restrict__ WV_b,
        const float* __restrict__ Wout_w, const float* __restrict__ Wout_b,
        const float* __restrict__ ln_g, const float* __restrict__ ln_b,
        const float* __restrict__ feat_w, const float* __restrict__ feat_b,
        const float* __restrict__ out_w, const float* __restrict__ out_b,
        const float* __restrict__ label_emb,
        float* __restrict__ ws, float* __restrict__ out) {
    unsigned* bar = (unsigned*)(ws + OFF_BAR);
    int t = threadIdx.x;
    int lane = t & 63;
    int wid = t >> 6;
    int wv = blockIdx.x * 3 + wid;   // 0..3071

    // ---- P0: block-redundant softmax + partial pool/maxes over 64-s chunk ---
    {
        __shared__ float red[256];
        __shared__ float al[64];
        __shared__ int lsf[64];
        __shared__ int lof[64];
        int b = blockIdx.x >> 3, chunk = blockIdx.x & 7;
        int s0 = chunk * 64;
        const float* sc = ws + OFF_SCORES + (size_t)b * SS;
        float v0 = sc[t], v1 = sc[t + 192], v2 = (t < 128) ? sc[t + 384] : NINF;
        red[t] = fmaxf(fmaxf(v0, v1), v2);
        if (t < 64) red[t + 192] = NINF;
        __syncthreads();
        for (int s2 = 128; s2 > 0; s2 >>= 1) {
            if (t < s2) red[t] = fmaxf(red[t], red[t + s2]);
            __syncthreads();
        }
        float m = red[0];
        __syncthreads();
        float e0 = expf(v0 - m) + expf(v1 - m) + ((t < 128) ? expf(v2 - m) : 0.f);
        red[t] = e0;
        if (t < 64) red[t + 192] = 0.f;
        __syncthreads();
        for (int s2 = 128; s2 > 0; s2 >>= 1) {
            if (t < s2) red[t] += red[t + s2];
            __syncthreads();
        }
        float inv = 1.0f / red[0];
        if (t < 64) {
            int gs = b * SS + s0 + t;
            al[t]  = expf(sc[s0 + t] - m) * inv;
            lsf[t] = (subj_pos[gs] == PPOS);
            lof[t] = (obj_pos[gs] == PPOS);
        }
        __syncthreads();
        const float4* in4 = (const float4*)inputs;
        float4 pool = make_float4(0.f, 0.f, 0.f, 0.f);
        float4 smax = make_float4(NINF, NINF, NINF, NINF);
        float4 omax = make_float4(NINF, NINF, NINF, NINF);
        for (int s = 0; s < 64; ++s) {
            float4 x = in4[((size_t)(b * SS + s0 + s)) * 192 + t];
            float a = al[s];
            pool.x += a * x.x; pool.y += a * x.y; pool.z += a * x.z; pool.w += a * x.w;
            if (lsf[s]) {
                smax.x = fmaxf(smax.x, x.x); smax.y = fmaxf(smax.y, x.y);
                smax.z = fmaxf(smax.z, x.z); smax.w = fmaxf(smax.w, x.w);
            }
            if (lof[s]) {
                omax.x = fmaxf(omax.x, x.x); omax.y = fmaxf(omax.y, x.y);
                omax.z = fmaxf(omax.z, x.z); omax.w = fmaxf(omax.w, x.w);
            }
        }
        size_t o = (size_t)(b * 8 + chunk) * 192 + t;
        ((float4*)(ws + OFF_PP))[o] = pool;
        ((float4*)(ws + OFF_PS))[o] = smax;
        ((float4*)(ws + OFF_PO))[o] = omax;
    }
    gbar(bar + 0, NBLK);

    // ---- P1: reduce 8 chunk partials -> pooled + CAT[subj|obj] ----
    {
        int i = blockIdx.x * NTHR + t;       // 0..196607
        if (i < BB * HH) {
            int b = i / HH, h = i - b * HH;
            float p = 0.f, sm = NINF, om = NINF;
            #pragma unroll
            for (int j = 0; j < 8; ++j) {
                int o = (b * 8 + j) * HH + h;
                p += ws[OFF_PP + o];
                sm = fmaxf(sm, ws[OFF_PS + o]);
                om = fmaxf(om, ws[OFF_PO + o]);
            }
            ws[OFF_POOLED + i] = p;
            ws[OFF_CAT + (size_t)b * 2304 + h] = sm;
            ws[OFF_CAT + (size_t)b * 2304 + 768 + h] = om;
        }
    }
    gbar(bar + 1, NBLK);

    // ---- P2: ctx_a = pooled @ WV_w.T + WV_b  (M=128,N=768,K=768) ----
    mm_phase<192, 0, 2>(ws + OFF_POOLED, WV_w, WV_b, ws + OFF_CTXA, BB, HH, wv, lane);
    gbar(bar + 2, NBLK);

    // ---- P3: ctx_b = gelu(ctx_a @ Wout_w.T + Wout_b) ----
    mm_phase<192, 1, 2>(ws + OFF_CTXA, Wout_w, Wout_b, ws + OFF_CTXB, BB, HH, wv, lane);
    gbar(bar + 3, NBLK);

    // ---- P4: layernorm -> out[5376..] and CAT[ctx] ----
    if (blockIdx.x < BB) {
        int b = blockIdx.x;
        const float* x = ws + OFF_CTXB + (size_t)b * HH;
        float a0 = x[t], a1 = x[t + 192], a2 = x[t + 384], a3 = x[t + 576];
        float s1 = a0 + a1 + a2 + a3;
        float s2 = a0*a0 + a1*a1 + a2*a2 + a3*a3;
        #pragma unroll
        for (int off = 32; off > 0; off >>= 1) {
            s1 += __shfl_xor(s1, off, 64);
            s2 += __shfl_xor(s2, off, 64);
        }
        __shared__ float rs[3], rq[3];
        if (lane == 0) { rs[wid] = s1; rq[wid] = s2; }
        __syncthreads();
        float S1 = rs[0] + rs[1] + rs[2], S2 = rq[0] + rq[1] + rq[2];
        float mu  = S1 * (1.0f / 768.0f);
        float var = S2 * (1.0f / 768.0f) - mu * mu;
        float inv = rsqrtf(var + 1e-5f);
        float* o  = out + 5376 + (size_t)b * HH;
        float* cc = ws + OFF_CAT + (size_t)b * 2304 + 1536;
        float r0 = (a0 - mu) * inv * ln_g[t]       + ln_b[t];
        float r1 = (a1 - mu) * inv * ln_g[t + 192] + ln_b[t + 192];
        float r2 = (a2 - mu) * inv * ln_g[t + 384] + ln_b[t + 384];
        float r3 = (a3 - mu) * inv * ln_g[t + 576] + ln_b[t + 576];
        o[t] = r0; o[t + 192] = r1; o[t + 384] = r2; o[t + 576] = r3;
        cc[t] = r0; cc[t + 192] = r1; cc[t + 384] = r2; cc[t + 576] = r3;
    }
    gbar(bar + 4, NBLK);

    // ---- P5: feats1 = gelu(cat @ feat_w.T + feat_b)  (K=2304, MT=4) ----
    mm_phase<576, 1, 4>(ws + OFF_CAT, feat_w, feat_b, ws + OFF_F1, BB, HH, wv, lane);
    gbar(bar + 5, NBLK);

    // ---- P6: feats2 = gelu(f1 @ out_w.T + out_b)  (N=300) ----
    mm_phase<192, 1, 2>(ws + OFF_F1, out_w, out_b, ws + OFF_F2, BB, 300, wv, lane);
    gbar(bar + 6, NBLK);

    // ---- P7: logits = f2 @ label_emb.T  (N=42) -> out[0..5376) ----
    mm_phase<75, 0, 2>(ws + OFF_F2, label_emb, nullptr, out, BB, 42, wv, lane);
}

extern "C" void kernel_launch(void* const* d_in, const int* in_sizes, int n_in,
                              void* d_out, int out_size, void* d_ws, size_t ws_size,
                              hipStream_t stream) {
    const float* inputs    = (const float*)d_in[0];
    const int*   pos_ids   = (const int*)d_in[1];
    const int*   subj_pos  = (const int*)d_in[3];
    const int*   obj_pos   = (const int*)d_in[4];
    const float* WQ        = (const float*)d_in[6];
    const float* bQ        = (const float*)d_in[7];
    const float* WK        = (const float*)d_in[8];
    const float* bK        = (const float*)d_in[9];
    const float* WV_w      = (const float*)d_in[10];
    const float* WV_b      = (const float*)d_in[11];
    const float* Wout_w    = (const float*)d_in[12];
    const float* Wout_b    = (const float*)d_in[13];
    const float* ln_g      = (const float*)d_in[14];
    const float* ln_b      = (const float*)d_in[15];
    const float* label_emb = (const float*)d_in[16];
    const float* feat_w    = (const float*)d_in[17];
    const float* feat_b    = (const float*)d_in[18];
    const float* out_w     = (const float*)d_in[19];
    const float* out_b     = (const float*)d_in[20];
    float* out = (float*)d_out;
    float* ws  = (float*)d_ws;

    k_kvec2  <<<656, 256, 0, stream>>>(label_emb, WK, bK, ws);
    k_weff2  <<<124, 256, 0, stream>>>(WQ, bQ, ws);
    k_scores <<<2048, 256, 0, stream>>>(inputs, pos_ids, subj_pos, obj_pos, ws);
    k_tail   <<<NBLK, NTHR, 0, stream>>>(inputs, subj_pos, obj_pos,
                                         WV_w, WV_b, Wout_w, Wout_b,
                                         ln_g, ln_b, feat_w, feat_b,
                                         out_w, out_b, label_emb, ws, out);
}

// Round 5
// 523.527 us; speedup vs baseline: 3.1433x; 3.1433x over previous
//
#include <hip/hip_runtime.h>
#include <math.h>

// Problem constants
#define BB 128
#define SS 512
#define HH 768
#define PPOS 512       // P
#define NEGC (-1.0e9f)
#define NINF (-1.0e12f)

// Workspace layout (float offsets). All regions DISJOINT (ws is plentiful).
#define OFF_KVEC   0          // 2624  (41*64)
#define OFF_WEFF   2624       // 768
#define OFF_C      3392       // 1
#define OFF_SCORES 4096       // 65536 (B*S) raw masked scores
#define OFF_PP     69632      // 1572864 (B*16*H) partial pooled
#define OFF_PS     1642496    // 1572864 partial subj max
#define OFF_PO     3215360    // 1572864 partial obj max
#define OFF_POOLED 4788224    // 98304 (B*H)
#define OFF_CAT    4886528    // 294912 (B*2304) [subj|obj|ctx]
#define OFF_CTXA   5181440    // 98304
#define OFF_CTXB   5279744    // 98304
#define OFF_F1     5378048    // 98304
#define OFF_F2     5476352    // 38400 (B*300)

__device__ __forceinline__ float gelu_f(float x) {
    return 0.5f * x * (1.0f + erff(x * 0.70710678118654752f));
}
__device__ __forceinline__ float dot4(float4 a, float4 b) {
    return a.x*b.x + a.y*b.y + a.z*b.z + a.w*b.w;
}

// ---------------------------------------------------------------------------
// Wave-tile GEMM: C[M,N] = act(A[M,K] @ W[N,K]^T + bias)
// Each wave computes a MT(m) x 16(n) tile. lane = (n_sub<<2) | k_sub:
// 16 n-groups x 4 k-lanes; k-lanes sweep K in float4 strides of 4.
// Cross-lane reduce = 2 shuffle steps.
// ---------------------------------------------------------------------------
template<int K4, int ACT, int MT>
__global__ __launch_bounds__(256) void k_mm(const float* __restrict__ A,
        const float* __restrict__ W, const float* __restrict__ bias,
        float* __restrict__ C, int M, int N) {
    int lane = threadIdx.x & 63;
    int wave = (blockIdx.x * 256 + threadIdx.x) >> 6;
    int ntn = (N + 15) >> 4;
    int m0 = (wave / ntn) * MT;
    if (m0 >= M) return;
    int n0 = ((wave % ntn) << 4) + (lane >> 2);
    int ks = lane & 3;
    bool nvalid = (n0 < N);
    const float4* w_row = (const float4*)W + (size_t)(nvalid ? n0 : 0) * K4;
    const float4* ar = (const float4*)A + (size_t)m0 * K4;
    float acc[MT];
    #pragma unroll
    for (int r = 0; r < MT; ++r) acc[r] = 0.f;
    #pragma unroll 4
    for (int j = ks; j < K4; j += 4) {
        float4 wv = w_row[j];
        #pragma unroll
        for (int r = 0; r < MT; ++r) acc[r] += dot4(ar[(size_t)r * K4 + j], wv);
    }
    #pragma unroll
    for (int r = 0; r < MT; ++r) {
        acc[r] += __shfl_xor(acc[r], 1, 64);
        acc[r] += __shfl_xor(acc[r], 2, 64);
    }
    if (ks == 0 && nvalid) {
        float b = bias ? bias[n0] : 0.f;
        #pragma unroll
        for (int r = 0; r < MT; ++r) {
            float v = acc[r] + b;
            if (ACT == 1) v = gelu_f(v);
            C[(size_t)(m0 + r) * N + n0] = v;
        }
    }
}

// K1a: kvec[l,k] = dot(label_emb[l+1], WK[l,k]) + bK. One wave/output.
// Blocks 0..3 zero-init WEFF and C for k_weff2's atomics.
__global__ __launch_bounds__(256) void k_kvec2(const float* __restrict__ label_emb,
        const float* __restrict__ WK, const float* __restrict__ bK,
        float* __restrict__ ws) {
    if (blockIdx.x < 3) ws[OFF_WEFF + blockIdx.x * 256 + threadIdx.x] = 0.f;
    if (blockIdx.x == 3 && threadIdx.x == 0) ws[OFF_C] = 0.f;
    int lane = threadIdx.x & 63;
    int idx = (blockIdx.x * 256 + threadIdx.x) >> 6;   // 0..2623
    int l = idx >> 6;
    const float4* lab4 = (const float4*)(label_emb + (size_t)(l + 1) * 300);
    const float4* wk4  = (const float4*)(WK + (size_t)idx * 300);
    float acc = dot4(lab4[lane], wk4[lane]);           // 75 float4s per row
    if (lane < 11) acc += dot4(lab4[64 + lane], wk4[64 + lane]);
    #pragma unroll
    for (int off = 32; off > 0; off >>= 1) acc += __shfl_xor(acc, off, 64);
    if (lane == 0) ws[OFF_KVEC + idx] = acc + bK[idx];
}

// K1b: w_eff[h] += kvec-chunk . WQ (atomics), + c = kvec.bQ
__global__ __launch_bounds__(256) void k_weff2(const float* __restrict__ WQ,
        const float* __restrict__ bQ, float* __restrict__ ws) {
    int lane = threadIdx.x & 63;
    int w = (blockIdx.x * 256 + threadIdx.x) >> 6;
    if (w < 492) {
        int jc = w / 12, hg = w % 12;
        int h = hg * 64 + lane;
        const float* wq = WQ + (size_t)(jc * 64) * HH + h;
        const float* kv = ws + OFF_KVEC + jc * 64;
        float acc = 0.f;
        #pragma unroll 8
        for (int j = 0; j < 64; ++j) acc += kv[j] * wq[(size_t)j * HH];
        atomicAdd(&ws[OFF_WEFF + h], acc);
    } else if (w == 492) {
        float acc = 0.f;
        for (int j = lane; j < 2624; j += 64) acc += ws[OFF_KVEC + j] * bQ[j];
        #pragma unroll
        for (int off = 32; off > 0; off >>= 1) acc += __shfl_xor(acc, off, 64);
        if (lane == 0) atomicAdd(&ws[OFF_C], acc);
    }
}

// K2: raw scores[row] = (x.w_eff + c)/8 + 41*mask*NEG. One wave/row, 8 rows/wave.
__global__ __launch_bounds__(256) void k_scores(const float* __restrict__ inputs,
        const int* __restrict__ pos_ids, const int* __restrict__ subj_pos,
        const int* __restrict__ obj_pos, float* __restrict__ ws) {
    int wave = threadIdx.x >> 6, lane = threadIdx.x & 63;
    const float4* in4 = (const float4*)inputs;
    const float4* w4  = (const float4*)(ws + OFF_WEFF);
    float c = ws[OFF_C];
    float4 w0 = w4[lane], w1 = w4[64 + lane], w2 = w4[128 + lane];
    int wid = blockIdx.x * 4 + wave;          // 0..8191
    for (int i = 0; i < 8; ++i) {
        int row = wid + 8192 * i;
        const float4* r4 = in4 + (size_t)row * 192;
        float acc = dot4(r4[lane], w0) + dot4(r4[64 + lane], w1) + dot4(r4[128 + lane], w2);
        #pragma unroll
        for (int off = 32; off > 0; off >>= 1) acc += __shfl_down(acc, off, 64);
        if (lane == 0) {
            bool m = (subj_pos[row] == PPOS) | (obj_pos[row] == PPOS) | (pos_ids[row] == 0);
            float sc = (acc + c) * 0.125f;
            if (m) sc += 41.0f * NEGC;
            ws[OFF_SCORES + row] = sc;
        }
    }
}

// K4: softmax (block-redundant per chunk) + partial attn-pool + masked maxes
// over a 32-s chunk. grid (16, B) = 2048 blocks -> 24 waves/CU. s-loop
// unrolled x2 for two outstanding loads.
__global__ __launch_bounds__(192) void k_pool(const float* __restrict__ inputs,
        const int* __restrict__ subj_pos, const int* __restrict__ obj_pos,
        float* __restrict__ ws) {
    __shared__ float red[256];
    __shared__ float al[32];
    __shared__ int lsf[32];
    __shared__ int lof[32];
    int chunk = blockIdx.x, b = blockIdx.y, t = threadIdx.x;
    int s0 = chunk * 32;
    const float* sc = ws + OFF_SCORES + (size_t)b * SS;
    // --- softmax over the full 512 scores of batch b (block-redundant) ---
    float v0 = sc[t], v1 = sc[t + 192], v2 = (t < 128) ? sc[t + 384] : NINF;
    red[t] = fmaxf(fmaxf(v0, v1), v2);
    if (t < 64) red[t + 192] = NINF;
    __syncthreads();
    for (int s2 = 128; s2 > 0; s2 >>= 1) {
        if (t < s2) red[t] = fmaxf(red[t], red[t + s2]);
        __syncthreads();
    }
    float m = red[0];
    __syncthreads();
    float e0 = expf(v0 - m) + expf(v1 - m) + ((t < 128) ? expf(v2 - m) : 0.f);
    red[t] = e0;
    if (t < 64) red[t + 192] = 0.f;
    __syncthreads();
    for (int s2 = 128; s2 > 0; s2 >>= 1) {
        if (t < s2) red[t] += red[t + s2];
        __syncthreads();
    }
    float inv = 1.0f / red[0];
    if (t < 32) {
        int gs = b * SS + s0 + t;
        al[t]  = expf(sc[s0 + t] - m) * inv;
        lsf[t] = (subj_pos[gs] == PPOS);
        lof[t] = (obj_pos[gs] == PPOS);
    }
    __syncthreads();
    // --- pool + masked maxes over this 32-row chunk (2 loads in flight) ---
    const float4* in4 = (const float4*)inputs;
    float4 pool = make_float4(0.f, 0.f, 0.f, 0.f);
    float4 smax = make_float4(NINF, NINF, NINF, NINF);
    float4 omax = make_float4(NINF, NINF, NINF, NINF);
    for (int s = 0; s < 32; s += 2) {
        float4 x0 = in4[((size_t)(b * SS + s0 + s)) * 192 + t];
        float4 x1 = in4[((size_t)(b * SS + s0 + s + 1)) * 192 + t];
        float a0 = al[s], a1 = al[s + 1];
        pool.x += a0 * x0.x; pool.y += a0 * x0.y; pool.z += a0 * x0.z; pool.w += a0 * x0.w;
        if (lsf[s]) {
            smax.x = fmaxf(smax.x, x0.x); smax.y = fmaxf(smax.y, x0.y);
            smax.z = fmaxf(smax.z, x0.z); smax.w = fmaxf(smax.w, x0.w);
        }
        if (lof[s]) {
            omax.x = fmaxf(omax.x, x0.x); omax.y = fmaxf(omax.y, x0.y);
            omax.z = fmaxf(omax.z, x0.z); omax.w = fmaxf(omax.w, x0.w);
        }
        pool.x += a1 * x1.x; pool.y += a1 * x1.y; pool.z += a1 * x1.z; pool.w += a1 * x1.w;
        if (lsf[s + 1]) {
            smax.x = fmaxf(smax.x, x1.x); smax.y = fmaxf(smax.y, x1.y);
            smax.z = fmaxf(smax.z, x1.z); smax.w = fmaxf(smax.w, x1.w);
        }
        if (lof[s + 1]) {
            omax.x = fmaxf(omax.x, x1.x); omax.y = fmaxf(omax.y, x1.y);
            omax.z = fmaxf(omax.z, x1.z); omax.w = fmaxf(omax.w, x1.w);
        }
    }
    size_t o = (size_t)(b * 16 + chunk) * 192 + t;
    ((float4*)(ws + OFF_PP))[o] = pool;
    ((float4*)(ws + OFF_PS))[o] = smax;
    ((float4*)(ws + OFF_PO))[o] = omax;
}

// K5: reduce 16 chunk partials -> pooled, and subj/obj maxes into CAT
__global__ void k_reduce(float* __restrict__ ws) {
    int i = blockIdx.x * 256 + threadIdx.x;   // 0..98303
    int b = i / HH, h = i - b * HH;
    float p = 0.f, sm = NINF, om = NINF;
    #pragma unroll
    for (int j = 0; j < 16; ++j) {
        int o = (b * 16 + j) * HH + h;
        p += ws[OFF_PP + o];
        sm = fmaxf(sm, ws[OFF_PS + o]);
        om = fmaxf(om, ws[OFF_PO + o]);
    }
    ws[OFF_POOLED + i] = p;
    ws[OFF_CAT + (size_t)b * 2304 + h] = sm;
    ws[OFF_CAT + (size_t)b * 2304 + 768 + h] = om;
}

// K8: layernorm -> ctx output (d_out offset 5376) AND cat[:, 1536:2304]
__global__ void k_ln(const float* __restrict__ ln_g, const float* __restrict__ ln_b,
                     float* __restrict__ ws, float* __restrict__ out) {
    __shared__ float red[256];
    __shared__ float red2[256];
    int b = blockIdx.x, t = threadIdx.x;
    const float* x = ws + OFF_CTXB + (size_t)b * HH;
    float a0 = x[t], a1 = x[t + 256], a2 = x[t + 512];
    red[t]  = a0 + a1 + a2;
    red2[t] = a0 * a0 + a1 * a1 + a2 * a2;
    __syncthreads();
    for (int s2 = 128; s2 > 0; s2 >>= 1) {
        if (t < s2) { red[t] += red[t + s2]; red2[t] += red2[t + s2]; }
        __syncthreads();
    }
    float mu  = red[0] * (1.0f / 768.0f);
    float var = red2[0] * (1.0f / 768.0f) - mu * mu;
    float inv = rsqrtf(var + 1e-5f);
    float* o = out + 5376 + (size_t)b * HH;
    float* cc = ws + OFF_CAT + (size_t)b * 2304 + 1536;
    float r0 = (a0 - mu) * inv * ln_g[t]       + ln_b[t];
    float r1 = (a1 - mu) * inv * ln_g[t + 256] + ln_b[t + 256];
    float r2 = (a2 - mu) * inv * ln_g[t + 512] + ln_b[t + 512];
    o[t] = r0; o[t + 256] = r1; o[t + 512] = r2;
    cc[t] = r0; cc[t + 256] = r1; cc[t + 512] = r2;
}

// K10: fused feats2 + logits. One block per batch row, 320 threads.
// f2 = gelu(f1[b] @ out_w.T + out_b) in LDS, then logits = f2 @ label_emb.T.
__global__ __launch_bounds__(320) void k_f2l(const float* __restrict__ out_w,
        const float* __restrict__ out_b, const float* __restrict__ label_emb,
        float* __restrict__ ws, float* __restrict__ out) {
    __shared__ __align__(16) float xr[768];
    __shared__ __align__(16) float f2s[300];
    int b = blockIdx.x, t = threadIdx.x;
    for (int i = t; i < 768; i += 320) xr[i] = ws[OFF_F1 + (size_t)b * HH + i];
    __syncthreads();
    if (t < 300) {
        const float4* w4 = (const float4*)(out_w + (size_t)t * HH);
        const float4* x4 = (const float4*)xr;
        float acc = out_b[t];
        #pragma unroll 4
        for (int q = 0; q < 192; ++q) acc += dot4(w4[q], x4[q]);
        f2s[t] = gelu_f(acc);
    }
    __syncthreads();
    if (t < 42) {
        const float4* l4 = (const float4*)(label_emb + (size_t)t * 300);
        const float4* x4 = (const float4*)f2s;
        float acc = 0.f;
        #pragma unroll 4
        for (int q = 0; q < 75; ++q) acc += dot4(l4[q], x4[q]);
        out[b * 42 + t] = acc;
    }
}

extern "C" void kernel_launch(void* const* d_in, const int* in_sizes, int n_in,
                              void* d_out, int out_size, void* d_ws, size_t ws_size,
                              hipStream_t stream) {
    const float* inputs    = (const float*)d_in[0];
    const int*   pos_ids   = (const int*)d_in[1];
    const int*   subj_pos  = (const int*)d_in[3];
    const int*   obj_pos   = (const int*)d_in[4];
    const float* WQ        = (const float*)d_in[6];
    const float* bQ        = (const float*)d_in[7];
    const float* WK        = (const float*)d_in[8];
    const float* bK        = (const float*)d_in[9];
    const float* WV_w      = (const float*)d_in[10];
    const float* WV_b      = (const float*)d_in[11];
    const float* Wout_w    = (const float*)d_in[12];
    const float* Wout_b    = (const float*)d_in[13];
    const float* ln_g      = (const float*)d_in[14];
    const float* ln_b      = (const float*)d_in[15];
    const float* label_emb = (const float*)d_in[16];
    const float* feat_w    = (const float*)d_in[17];
    const float* feat_b    = (const float*)d_in[18];
    const float* out_w     = (const float*)d_in[19];
    const float* out_b     = (const float*)d_in[20];
    float* out = (float*)d_out;
    float* ws  = (float*)d_ws;

    k_kvec2  <<<656, 256, 0, stream>>>(label_emb, WK, bK, ws);
    k_weff2  <<<124, 256, 0, stream>>>(WQ, bQ, ws);
    k_scores <<<2048, 256, 0, stream>>>(inputs, pos_ids, subj_pos, obj_pos, ws);
    k_pool   <<<dim3(16, BB), 192, 0, stream>>>(inputs, subj_pos, obj_pos, ws);
    k_reduce <<<384, 256, 0, stream>>>(ws);
    // ctx_a = pooled @ WV_w.T + WV_b          (M=128,N=768,K=768)
    k_mm<192,0,2><<<768, 256, 0, stream>>>(ws + OFF_POOLED, WV_w, WV_b, ws + OFF_CTXA, BB, HH);
    // ctx_b = gelu(ctx_a @ Wout_w.T + Wout_b) (M=128,N=768,K=768)
    k_mm<192,1,2><<<768, 256, 0, stream>>>(ws + OFF_CTXA, Wout_w, Wout_b, ws + OFF_CTXB, BB, HH);
    k_ln     <<<BB, 256, 0, stream>>>(ln_g, ln_b, ws, out);
    // feats1 = gelu(cat @ feat_w.T + feat_b)  (M=128,N=768,K=2304, MT=4)
    k_mm<576,1,4><<<384, 256, 0, stream>>>(ws + OFF_CAT, feat_w, feat_b, ws + OFF_F1, BB, HH);
    // feats2 + logits fused
    k_f2l    <<<BB, 320, 0, stream>>>(out_w, out_b, label_emb, ws, out);
}